// Round 6
// baseline (2405.178 us; speedup 1.0000x reference)
//
#include <hip/hip_runtime.h>

#define N_ENEMY 4000000
#define N_GUN   1000000
#define N_EDGES 16000000
#define HID     64
#define OUTD    8

#define NB 1024                  // buckets (977 guns each)
#define GPB 977                  // guns per bucket
#define TILE 8192                // edges per scatter tile
#define EPT 32                   // edges per thread (TILE/256)
#define NTILE 1954               // ceil(16M / 8192)

#define NS 16                    // src slices (256K enemies = 2MB bf16 each)
#define SEG_CAP 16128            // slice_sort LDS capacity (mean 15625, +4 sigma)
#define SPIN_LIMIT 48            // best-effort barrier spin cap (~50us)

// exact floor(dst/977) for dst <= 1M (verified: 977*1125395730 = 2^40 + 434)
__device__ __forceinline__ unsigned int bucket_of(unsigned int dst) {
    return (unsigned int)(((unsigned long long)dst * 1125395730ull) >> 40);
}

// ---- Fold W_l@W_fc (4x8), W_r@W_fc (8), b_l@W_fc + b_fc (8) into P[48] ----
__global__ void prep_params(const float* __restrict__ W_l, const float* __restrict__ b_l,
                            const float* __restrict__ W_r, const float* __restrict__ W_fc,
                            const float* __restrict__ b_fc, float* __restrict__ P) {
    int o = threadIdx.x;
    if (o < OUTD) {
        float a0 = 0.f, a1 = 0.f, a2 = 0.f, a3 = 0.f, r = 0.f, c = 0.f;
        for (int h = 0; h < HID; ++h) {
            float w = W_fc[h * OUTD + o];
            a0 += W_l[0 * HID + h] * w;
            a1 += W_l[1 * HID + h] * w;
            a2 += W_l[2 * HID + h] * w;
            a3 += W_l[3 * HID + h] * w;
            r  += W_r[h] * w;
            c  += b_l[h] * w;
        }
        P[0 * OUTD + o] = a0;
        P[1 * OUTD + o] = a1;
        P[2 * OUTD + o] = a2;
        P[3 * OUTD + o] = a3;
        P[4 * OUTD + o] = r;
        P[5 * OUTD + o] = c + b_fc[o];
    }
}

// ---- Convert x_enemy f32x4 -> bf16x4 (packed into uint2) ----
__device__ __forceinline__ unsigned int rne_bf16(unsigned int u) {
    return (u + 0x7FFFu + ((u >> 16) & 1u)) >> 16;
}
__global__ void conv_kernel(const uint4* __restrict__ xe, uint2* __restrict__ xeb) {
    int i = blockIdx.x * blockDim.x + threadIdx.x;
    if (i >= N_ENEMY) return;
    uint4 v = xe[i];
    uint2 q;
    q.x = rne_bf16(v.x) | (rne_bf16(v.y) << 16);
    q.y = rne_bf16(v.z) | (rne_bf16(v.w) << 16);
    xeb[i] = q;
}

// ---- Phase A: per-bucket histogram ----
#define CHUNK4 15625
__global__ void hist_kernel(const int4* __restrict__ edst4, unsigned int* __restrict__ hist) {
    __shared__ unsigned int lh[NB];
    for (int i = threadIdx.x; i < NB; i += 256) lh[i] = 0;
    __syncthreads();
    int base = blockIdx.x * CHUNK4;
    for (int i = threadIdx.x; i < CHUNK4; i += 256) {
        int4 d = edst4[base + i];
        atomicAdd(&lh[bucket_of((unsigned)d.x)], 1u);
        atomicAdd(&lh[bucket_of((unsigned)d.y)], 1u);
        atomicAdd(&lh[bucket_of((unsigned)d.z)], 1u);
        atomicAdd(&lh[bucket_of((unsigned)d.w)], 1u);
    }
    __syncthreads();
    for (int i = threadIdx.x; i < NB; i += 256)
        if (lh[i]) atomicAdd(&hist[i], lh[i]);
}

// ---- Phase B: exclusive scan -> offsets[NB+1], cursor[NB] ----
__global__ void scan_kernel(const unsigned int* __restrict__ hist,
                            unsigned int* __restrict__ offsets,
                            unsigned int* __restrict__ cursor) {
    __shared__ unsigned int tmp[1024];
    int t = threadIdx.x;
    unsigned int v0 = (t < NB) ? hist[t] : 0u;
    tmp[t] = v0;
    __syncthreads();
    for (int d = 1; d < 1024; d <<= 1) {
        unsigned int v = (t >= d) ? tmp[t - d] : 0u;
        __syncthreads();
        tmp[t] += v;
        __syncthreads();
    }
    if (t < NB) {
        unsigned int excl = tmp[t] - v0;
        offsets[t] = excl;
        cursor[t]  = excl;
    }
    if (t == NB - 1) offsets[NB] = tmp[t];
}

// ---- Phase C: tile-sorted partition by bucket ----
// payload word: (src << 10) | g   where g = dst - bucket*977  (g < 977)
__global__ __launch_bounds__(256, 2)
void scatter_sorted(const int* __restrict__ esrc, const int* __restrict__ edst,
                    unsigned int* __restrict__ cursor, unsigned int* __restrict__ payload) {
    __shared__ unsigned int cnt[NB];
    __shared__ unsigned int base[NB];
    __shared__ unsigned int gb[NB];
    __shared__ unsigned short bOf[TILE];
    __shared__ unsigned int sorted[TILE];
    __shared__ unsigned int partial[256];

    int t = threadIdx.x;
    int ebase = blockIdx.x * TILE;
    int nE = N_EDGES - ebase;
    if (nE > TILE) nE = TILE;

    for (int i = t; i < NB; i += 256) cnt[i] = 0;
    __syncthreads();

    unsigned int w[EPT];
    unsigned int br[EPT];
#pragma unroll
    for (int k = 0; k < EPT; ++k) {
        int idx = k * 256 + t;
        if (idx < nE) {
            unsigned int s = (unsigned int)esrc[ebase + idx];
            unsigned int d = (unsigned int)edst[ebase + idx];
            unsigned int b = bucket_of(d);
            unsigned int g = d - b * GPB;
            unsigned int r = atomicAdd(&cnt[b], 1u);
            w[k]  = (s << 10) | g;
            br[k] = (b << 13) | r;
        } else {
            br[k] = 0xFFFFFFFFu;
        }
    }
    __syncthreads();

    unsigned int loc[4];
    unsigned int s = 0;
#pragma unroll
    for (int j = 0; j < 4; ++j) {
        int b = t * 4 + j;
        unsigned int c = cnt[b];
        loc[j] = s;
        s += c;
    }
    partial[t] = s;
    __syncthreads();
    for (int d = 1; d < 256; d <<= 1) {
        unsigned int v = (t >= d) ? partial[t - d] : 0u;
        __syncthreads();
        partial[t] += v;
        __syncthreads();
    }
    unsigned int excl = (t > 0) ? partial[t - 1] : 0u;
#pragma unroll
    for (int j = 0; j < 4; ++j) {
        int b = t * 4 + j;
        base[b] = excl + loc[j];
    }
    __syncthreads();

#pragma unroll
    for (int j = 0; j < 4; ++j) {
        int b = t * 4 + j;
        unsigned int c = cnt[b];
        unsigned int g = c ? atomicAdd(&cursor[b], c) : 0u;
        gb[b] = g;
        unsigned int bs = base[b];
        for (unsigned int p = bs; p < bs + c; ++p) bOf[p] = (unsigned short)b;
    }
    __syncthreads();

#pragma unroll
    for (int k = 0; k < EPT; ++k) {
        if (br[k] != 0xFFFFFFFFu) {
            unsigned int b = br[k] >> 13;
            unsigned int r = br[k] & 8191u;
            sorted[base[b] + r] = w[k];
        }
    }
    __syncthreads();

    for (int p = t; p < nE; p += 256) {
        unsigned int b = bOf[p];
        payload[gb[b] + ((unsigned int)p - base[b])] = sorted[p];
    }
}

// ---- Phase C2: per-bucket counting sort by src-slice (slice = w>>28), <=64KB LDS ----
// stab[b][k] (k=0..NS): absolute run starts; stab[b][NS] = segment end.
__global__ __launch_bounds__(256)
void slice_sort(const unsigned int* __restrict__ offsets,
                unsigned int* __restrict__ payload,
                unsigned int* __restrict__ stab) {
    __shared__ unsigned int A[SEG_CAP];
    __shared__ unsigned int cnt[NS];
    __shared__ unsigned int base[NS + 1];
    int b = blockIdx.x;
    int t = threadIdx.x;
    unsigned int segS = offsets[b];
    unsigned int segE = offsets[b + 1];
    unsigned int len = segE - segS;

    if (len > SEG_CAP) {
        // graceful fallback: single run covering everything (loses locality only)
        if (t <= NS) stab[b * (NS + 1) + t] = (t == 0) ? segS : segE;
        return;
    }
    if (t < NS) cnt[t] = 0;
    __syncthreads();
    for (unsigned int i = t; i < len; i += 256) {
        unsigned int w = payload[segS + i];
        A[i] = w;
        atomicAdd(&cnt[w >> 28], 1u);
    }
    __syncthreads();
    if (t == 0) {
        unsigned int acc = 0;
        for (int k = 0; k < NS; ++k) { base[k] = acc; acc += cnt[k]; }
        base[NS] = acc;
    }
    __syncthreads();
    if (t < NS) cnt[t] = 0;
    __syncthreads();
    // sorted write-back straight to global (scatter stays inside 64KB segment -> L2)
    for (unsigned int i = t; i < len; i += 256) {
        unsigned int w = A[i];
        unsigned int k = w >> 28;
        unsigned int r = atomicAdd(&cnt[k], 1u);
        payload[segS + base[k] + r] = w;
    }
    if (t <= NS) stab[b * (NS + 1) + t] = segS + base[t];
}

// ---- best-effort grid barrier: bounded spin, giveup flag; perf-only, hang-free ----
__device__ __forceinline__ void soft_barrier(unsigned int* bar, unsigned int* giveup, int s) {
    __syncthreads();
    if (threadIdx.x == 0) {
        if (!__hip_atomic_load(giveup, __ATOMIC_RELAXED, __HIP_MEMORY_SCOPE_AGENT)) {
            unsigned int arrived = __hip_atomic_fetch_add(&bar[s], 1u, __ATOMIC_ACQ_REL,
                                                          __HIP_MEMORY_SCOPE_AGENT) + 1u;
            if (arrived < (unsigned int)NB) {
                int iters = 0;
                while (__hip_atomic_load(&bar[s], __ATOMIC_ACQUIRE,
                                         __HIP_MEMORY_SCOPE_AGENT) < (unsigned int)NB) {
                    if (__hip_atomic_load(giveup, __ATOMIC_RELAXED,
                                          __HIP_MEMORY_SCOPE_AGENT)) break;
                    if (++iters > SPIN_LIMIT) {
                        __hip_atomic_store(giveup, 1u, __ATOMIC_RELAXED,
                                           __HIP_MEMORY_SCOPE_AGENT);
                        break;
                    }
                    __builtin_amdgcn_s_sleep(32);
                }
            }
        }
    }
    __syncthreads();
}

// ---- Phase D: slice-lockstep (best-effort) aggregate + folded affine epilogue ----
__global__ __launch_bounds__(256)
void bucket_v7(const unsigned int* __restrict__ stab,
               const unsigned int* __restrict__ payload,
               const uint2* __restrict__ xeb,
               const float* __restrict__ xg,
               const float* __restrict__ P,
               float* __restrict__ out,
               unsigned int* bar, unsigned int* giveup) {
    __shared__ float s0[1024], s1[1024], s2[1024], s3[1024];
    __shared__ unsigned int cc[1024];
    __shared__ float sP[48];
    int t = threadIdx.x;
    for (int i = t; i < 1024; i += 256) {
        s0[i] = 0.f; s1[i] = 0.f; s2[i] = 0.f; s3[i] = 0.f; cc[i] = 0u;
    }
    if (t < 48) sP[t] = P[t];
    __syncthreads();

    unsigned int b = blockIdx.x;

    for (int s = 0; s < NS; ++s) {
        unsigned int rs = stab[b * (NS + 1) + s];
        unsigned int re = stab[b * (NS + 1) + s + 1];
        unsigned int i = rs + (unsigned int)t;
        for (; i + 256 < re; i += 512) {
            unsigned int p0 = payload[i];
            unsigned int p1 = payload[i + 256];
            uint2 q0 = xeb[p0 >> 10];
            uint2 q1 = xeb[p1 >> 10];
            unsigned int g0 = p0 & 1023u, g1 = p1 & 1023u;
            atomicAdd(&s0[g0], __uint_as_float(q0.x << 16));
            atomicAdd(&s1[g0], __uint_as_float(q0.x & 0xffff0000u));
            atomicAdd(&s2[g0], __uint_as_float(q0.y << 16));
            atomicAdd(&s3[g0], __uint_as_float(q0.y & 0xffff0000u));
            atomicAdd(&cc[g0], 1u);
            atomicAdd(&s0[g1], __uint_as_float(q1.x << 16));
            atomicAdd(&s1[g1], __uint_as_float(q1.x & 0xffff0000u));
            atomicAdd(&s2[g1], __uint_as_float(q1.y << 16));
            atomicAdd(&s3[g1], __uint_as_float(q1.y & 0xffff0000u));
            atomicAdd(&cc[g1], 1u);
        }
        if (i < re) {
            unsigned int p0 = payload[i];
            uint2 q0 = xeb[p0 >> 10];
            unsigned int g0 = p0 & 1023u;
            atomicAdd(&s0[g0], __uint_as_float(q0.x << 16));
            atomicAdd(&s1[g0], __uint_as_float(q0.x & 0xffff0000u));
            atomicAdd(&s2[g0], __uint_as_float(q0.y << 16));
            atomicAdd(&s3[g0], __uint_as_float(q0.y & 0xffff0000u));
            atomicAdd(&cc[g0], 1u);
        }
        if (s != NS - 1) soft_barrier(bar, giveup, s);
    }
    __syncthreads();

    for (int g = t; g < 1024; g += 256) {
        if (g >= GPB) continue;
        unsigned int G = b * GPB + (unsigned int)g;
        if (G >= N_GUN) continue;
        float cnt = (float)cc[g];
        float inv = 1.0f / fmaxf(cnt, 1.0f);
        float m0 = s0[g] * inv, m1 = s1[g] * inv, m2 = s2[g] * inv, m3 = s3[g] * inv;
        float xv = xg[G];
        float res[OUTD];
#pragma unroll
        for (int o = 0; o < OUTD; ++o) {
            res[o] = m0 * sP[o] + m1 * sP[8 + o] + m2 * sP[16 + o] + m3 * sP[24 + o]
                   + xv * sP[32 + o] + sP[40 + o];
        }
        float4* op = (float4*)(out + (size_t)G * OUTD);
        op[0] = make_float4(res[0], res[1], res[2], res[3]);
        op[1] = make_float4(res[4], res[5], res[6], res[7]);
    }
}

// ================= fallback (atomic path, ~20 MB ws) ========================
__global__ void edge_kernel(const int4* __restrict__ esrc4, const int4* __restrict__ edst4,
                            const float4* __restrict__ xe, float* __restrict__ summed,
                            float* __restrict__ counts) {
    int t = blockIdx.x * blockDim.x + threadIdx.x;
    if (t >= N_EDGES / 4) return;
    int4 s4 = esrc4[t];
    int4 d4 = edst4[t];
    int ss[4] = { s4.x, s4.y, s4.z, s4.w };
    int dd[4] = { d4.x, d4.y, d4.z, d4.w };
#pragma unroll
    for (int k = 0; k < 4; ++k) {
        float4 m = xe[ss[k]];
        float* basep = summed + (size_t)dd[k] * 4;
        atomicAdd(basep + 0, m.x);
        atomicAdd(basep + 1, m.y);
        atomicAdd(basep + 2, m.z);
        atomicAdd(basep + 3, m.w);
        atomicAdd(counts + dd[k], 1.0f);
    }
}

__global__ void gun_kernel(const float4* __restrict__ summed, const float* __restrict__ counts,
                           const float* __restrict__ xg, const float* __restrict__ P,
                           float* __restrict__ out) {
    __shared__ float sP[48];
    if (threadIdx.x < 48) sP[threadIdx.x] = P[threadIdx.x];
    __syncthreads();
    int g = blockIdx.x * blockDim.x + threadIdx.x;
    if (g >= N_GUN) return;
    float4 s = summed[g];
    float cnt = counts[g];
    float inv = 1.0f / fmaxf(cnt, 1.0f);
    float m0 = s.x * inv, m1 = s.y * inv, m2 = s.z * inv, m3 = s.w * inv;
    float xv = xg[g];
    float res[OUTD];
#pragma unroll
    for (int o = 0; o < OUTD; ++o) {
        res[o] = m0 * sP[o] + m1 * sP[8 + o] + m2 * sP[16 + o] + m3 * sP[24 + o]
               + xv * sP[32 + o] + sP[40 + o];
    }
    float4* op = (float4*)(out + (size_t)g * OUTD);
    op[0] = make_float4(res[0], res[1], res[2], res[3]);
    op[1] = make_float4(res[4], res[5], res[6], res[7]);
}

extern "C" void kernel_launch(void* const* d_in, const int* in_sizes, int n_in,
                              void* d_out, int out_size, void* d_ws, size_t ws_size,
                              hipStream_t stream) {
    const float* x_enemy = (const float*)d_in[0];
    const float* x_gun   = (const float*)d_in[1];
    const int*   esrc    = (const int*)d_in[2];
    const int*   edst    = (const int*)d_in[3];
    const float* W_l     = (const float*)d_in[4];
    const float* b_l     = (const float*)d_in[5];
    const float* W_r     = (const float*)d_in[6];
    const float* W_fc    = (const float*)d_in[7];
    const float* b_fc    = (const float*)d_in[8];
    float* out = (float*)d_out;

    // ws layout (u32 units)
    const size_t PAYLOAD_OFF = 0;                            // 16M u32 = 64 MB
    const size_t XEB_OFF     = (size_t)N_EDGES;              // 4M uint2 = 32 MB
    const size_t HIST_OFF    = XEB_OFF + (size_t)N_ENEMY*2;  // +1024 (zeroed)
    const size_t BAR_OFF     = HIST_OFF + NB;                // +16   (zeroed)
    const size_t GU_OFF      = BAR_OFF + NS;                 // +1    (zeroed)
    const size_t OFFS_OFF    = GU_OFF + 1;                   // +1025
    const size_t CURS_OFF    = OFFS_OFF + NB + 1;            // +1024
    const size_t P_OFF       = CURS_OFF + NB;                // +48
    const size_t STAB_OFF    = P_OFF + 48;                   // +NB*(NS+1)
    const size_t NEEDED_FULL = (STAB_OFF + (size_t)NB * (NS + 1)) * sizeof(unsigned int);

    if (ws_size >= NEEDED_FULL) {
        unsigned int* ws      = (unsigned int*)d_ws;
        unsigned int* payload = ws + PAYLOAD_OFF;
        uint2*        xeb     = (uint2*)(ws + XEB_OFF);
        unsigned int* hist    = ws + HIST_OFF;
        unsigned int* bar     = ws + BAR_OFF;
        unsigned int* giveup  = ws + GU_OFF;
        unsigned int* offsets = ws + OFFS_OFF;
        unsigned int* cursor  = ws + CURS_OFF;
        float*        P       = (float*)(ws + P_OFF);
        unsigned int* stab    = ws + STAB_OFF;

        hipMemsetAsync(hist, 0, (NB + NS + 1) * sizeof(unsigned int), stream);
        prep_params<<<1, 64, 0, stream>>>(W_l, b_l, W_r, W_fc, b_fc, P);
        conv_kernel<<<(N_ENEMY + 255) / 256, 256, 0, stream>>>((const uint4*)x_enemy, xeb);
        hist_kernel<<<256, 256, 0, stream>>>((const int4*)edst, hist);
        scan_kernel<<<1, 1024, 0, stream>>>(hist, offsets, cursor);
        scatter_sorted<<<NTILE, 256, 0, stream>>>(esrc, edst, cursor, payload);
        slice_sort<<<NB, 256, 0, stream>>>(offsets, payload, stab);
        bucket_v7<<<NB, 256, 0, stream>>>(stab, payload, xeb, x_gun, P, out, bar, giveup);
    } else {
        float* summed = (float*)d_ws;
        float* counts = summed + (size_t)N_GUN * 4;
        float* P      = counts + N_GUN;
        hipMemsetAsync(d_ws, 0, ((size_t)N_GUN * 5 + 48) * sizeof(float), stream);
        prep_params<<<1, 64, 0, stream>>>(W_l, b_l, W_r, W_fc, b_fc, P);
        int edge_threads = N_EDGES / 4;
        edge_kernel<<<(edge_threads + 255) / 256, 256, 0, stream>>>(
            (const int4*)esrc, (const int4*)edst, (const float4*)x_enemy, summed, counts);
        gun_kernel<<<(N_GUN + 255) / 256, 256, 0, stream>>>(
            (const float4*)summed, counts, x_gun, P, out);
    }
}

// Round 7
// 1632.859 us; speedup vs baseline: 1.4730x; 1.4730x over previous
//
#include <hip/hip_runtime.h>

#define N_ENEMY 4000000
#define N_GUN   1000000
#define N_EDGES 16000000
#define HID     64
#define OUTD    8

#define NB 1024                  // buckets (977 guns each)
#define GPB 977                  // guns per bucket
#define TILE 8192                // edges per scatter tile
#define EPT 32                   // edges per thread (TILE/256)
#define NTILE 1954               // ceil(16M / 8192)

#define NS 16                    // src slices (256K enemies = 2MB bf16 each)
#define SEG_CAP 16128            // slice_sort LDS capacity (mean 15625, +4 sigma)
#define SPIN_LIMIT 512           // ~0.2us * 512 = ~100us cap, perf-only

// exact floor(dst/977) for dst <= 1M
__device__ __forceinline__ unsigned int bucket_of(unsigned int dst) {
    return (unsigned int)(((unsigned long long)dst * 1125395730ull) >> 40);
}

// ---- Fold W_l@W_fc (4x8), W_r@W_fc (8), b_l@W_fc + b_fc (8) into P[48] ----
__global__ void prep_params(const float* __restrict__ W_l, const float* __restrict__ b_l,
                            const float* __restrict__ W_r, const float* __restrict__ W_fc,
                            const float* __restrict__ b_fc, float* __restrict__ P) {
    int o = threadIdx.x;
    if (o < OUTD) {
        float a0 = 0.f, a1 = 0.f, a2 = 0.f, a3 = 0.f, r = 0.f, c = 0.f;
        for (int h = 0; h < HID; ++h) {
            float w = W_fc[h * OUTD + o];
            a0 += W_l[0 * HID + h] * w;
            a1 += W_l[1 * HID + h] * w;
            a2 += W_l[2 * HID + h] * w;
            a3 += W_l[3 * HID + h] * w;
            r  += W_r[h] * w;
            c  += b_l[h] * w;
        }
        P[0 * OUTD + o] = a0;
        P[1 * OUTD + o] = a1;
        P[2 * OUTD + o] = a2;
        P[3 * OUTD + o] = a3;
        P[4 * OUTD + o] = r;
        P[5 * OUTD + o] = c + b_fc[o];
    }
}

// ---- Convert x_enemy f32x4 -> bf16x4 (packed into uint2) ----
__device__ __forceinline__ unsigned int rne_bf16(unsigned int u) {
    return (u + 0x7FFFu + ((u >> 16) & 1u)) >> 16;
}
__global__ void conv_kernel(const uint4* __restrict__ xe, uint2* __restrict__ xeb) {
    int i = blockIdx.x * blockDim.x + threadIdx.x;
    if (i >= N_ENEMY) return;
    uint4 v = xe[i];
    uint2 q;
    q.x = rne_bf16(v.x) | (rne_bf16(v.y) << 16);
    q.y = rne_bf16(v.z) | (rne_bf16(v.w) << 16);
    xeb[i] = q;
}

// ---- Phase A: per-bucket histogram ----
#define CHUNK4 15625
__global__ void hist_kernel(const int4* __restrict__ edst4, unsigned int* __restrict__ hist) {
    __shared__ unsigned int lh[NB];
    for (int i = threadIdx.x; i < NB; i += 256) lh[i] = 0;
    __syncthreads();
    int base = blockIdx.x * CHUNK4;
    for (int i = threadIdx.x; i < CHUNK4; i += 256) {
        int4 d = edst4[base + i];
        atomicAdd(&lh[bucket_of((unsigned)d.x)], 1u);
        atomicAdd(&lh[bucket_of((unsigned)d.y)], 1u);
        atomicAdd(&lh[bucket_of((unsigned)d.z)], 1u);
        atomicAdd(&lh[bucket_of((unsigned)d.w)], 1u);
    }
    __syncthreads();
    for (int i = threadIdx.x; i < NB; i += 256)
        if (lh[i]) atomicAdd(&hist[i], lh[i]);
}

// ---- Phase B: exclusive scan -> offsets[NB+1], cursor[NB] ----
__global__ void scan_kernel(const unsigned int* __restrict__ hist,
                            unsigned int* __restrict__ offsets,
                            unsigned int* __restrict__ cursor) {
    __shared__ unsigned int tmp[1024];
    int t = threadIdx.x;
    unsigned int v0 = (t < NB) ? hist[t] : 0u;
    tmp[t] = v0;
    __syncthreads();
    for (int d = 1; d < 1024; d <<= 1) {
        unsigned int v = (t >= d) ? tmp[t - d] : 0u;
        __syncthreads();
        tmp[t] += v;
        __syncthreads();
    }
    if (t < NB) {
        unsigned int excl = tmp[t] - v0;
        offsets[t] = excl;
        cursor[t]  = excl;
    }
    if (t == NB - 1) offsets[NB] = tmp[t];
}

// ---- Phase C: tile-sorted partition by bucket ----
// payload word: (src << 10) | g   where g = dst - bucket*977  (g < 977)
__global__ __launch_bounds__(256, 2)
void scatter_sorted(const int* __restrict__ esrc, const int* __restrict__ edst,
                    unsigned int* __restrict__ cursor, unsigned int* __restrict__ payload) {
    __shared__ unsigned int cnt[NB];
    __shared__ unsigned int base[NB];
    __shared__ unsigned int gb[NB];
    __shared__ unsigned short bOf[TILE];
    __shared__ unsigned int sorted[TILE];
    __shared__ unsigned int partial[256];

    int t = threadIdx.x;
    int ebase = blockIdx.x * TILE;
    int nE = N_EDGES - ebase;
    if (nE > TILE) nE = TILE;

    for (int i = t; i < NB; i += 256) cnt[i] = 0;
    __syncthreads();

    unsigned int w[EPT];
    unsigned int br[EPT];
#pragma unroll
    for (int k = 0; k < EPT; ++k) {
        int idx = k * 256 + t;
        if (idx < nE) {
            unsigned int s = (unsigned int)esrc[ebase + idx];
            unsigned int d = (unsigned int)edst[ebase + idx];
            unsigned int b = bucket_of(d);
            unsigned int g = d - b * GPB;
            unsigned int r = atomicAdd(&cnt[b], 1u);
            w[k]  = (s << 10) | g;
            br[k] = (b << 13) | r;
        } else {
            br[k] = 0xFFFFFFFFu;
        }
    }
    __syncthreads();

    unsigned int loc[4];
    unsigned int s = 0;
#pragma unroll
    for (int j = 0; j < 4; ++j) {
        int b = t * 4 + j;
        unsigned int c = cnt[b];
        loc[j] = s;
        s += c;
    }
    partial[t] = s;
    __syncthreads();
    for (int d = 1; d < 256; d <<= 1) {
        unsigned int v = (t >= d) ? partial[t - d] : 0u;
        __syncthreads();
        partial[t] += v;
        __syncthreads();
    }
    unsigned int excl = (t > 0) ? partial[t - 1] : 0u;
#pragma unroll
    for (int j = 0; j < 4; ++j) {
        int b = t * 4 + j;
        base[b] = excl + loc[j];
    }
    __syncthreads();

#pragma unroll
    for (int j = 0; j < 4; ++j) {
        int b = t * 4 + j;
        unsigned int c = cnt[b];
        unsigned int g = c ? atomicAdd(&cursor[b], c) : 0u;
        gb[b] = g;
        unsigned int bs = base[b];
        for (unsigned int p = bs; p < bs + c; ++p) bOf[p] = (unsigned short)b;
    }
    __syncthreads();

#pragma unroll
    for (int k = 0; k < EPT; ++k) {
        if (br[k] != 0xFFFFFFFFu) {
            unsigned int b = br[k] >> 13;
            unsigned int r = br[k] & 8191u;
            sorted[base[b] + r] = w[k];
        }
    }
    __syncthreads();

    for (int p = t; p < nE; p += 256) {
        unsigned int b = bOf[p];
        payload[gb[b] + ((unsigned int)p - base[b])] = sorted[p];
    }
}

// ---- Phase C2: per-bucket counting sort by src-slice (slice = w>>28), <=64KB LDS ----
__global__ __launch_bounds__(256)
void slice_sort(const unsigned int* __restrict__ offsets,
                unsigned int* __restrict__ payload,
                unsigned int* __restrict__ stab) {
    __shared__ unsigned int A[SEG_CAP];
    __shared__ unsigned int cnt[NS];
    __shared__ unsigned int base[NS + 1];
    int b = blockIdx.x;
    int t = threadIdx.x;
    unsigned int segS = offsets[b];
    unsigned int segE = offsets[b + 1];
    unsigned int len = segE - segS;

    if (len > SEG_CAP) {
        if (t <= NS) stab[b * (NS + 1) + t] = (t == 0) ? segS : segE;
        return;
    }
    if (t < NS) cnt[t] = 0;
    __syncthreads();
    for (unsigned int i = t; i < len; i += 256) {
        unsigned int w = payload[segS + i];
        A[i] = w;
        atomicAdd(&cnt[w >> 28], 1u);
    }
    __syncthreads();
    if (t == 0) {
        unsigned int acc = 0;
        for (int k = 0; k < NS; ++k) { base[k] = acc; acc += cnt[k]; }
        base[NS] = acc;
    }
    __syncthreads();
    if (t < NS) cnt[t] = 0;
    __syncthreads();
    for (unsigned int i = t; i < len; i += 256) {
        unsigned int w = A[i];
        unsigned int k = w >> 28;
        unsigned int r = atomicAdd(&cnt[k], 1u);
        payload[segS + base[k] + r] = w;
    }
    if (t <= NS) stab[b * (NS + 1) + t] = segS + base[t];
}

// ---- best-effort grid barrier: ALL-RELAXED (no cache maintenance), bounded spin ----
// Barrier is performance-only (no data crosses it) -> zero memory ordering needed.
__device__ __forceinline__ void soft_barrier(unsigned int* bar, unsigned int* giveup, int s) {
    __syncthreads();
    if (threadIdx.x == 0) {
        if (!__hip_atomic_load(giveup, __ATOMIC_RELAXED, __HIP_MEMORY_SCOPE_AGENT)) {
            unsigned int arrived = __hip_atomic_fetch_add(&bar[s], 1u, __ATOMIC_RELAXED,
                                                          __HIP_MEMORY_SCOPE_AGENT) + 1u;
            if (arrived < (unsigned int)NB) {
                int iters = 0;
                while (__hip_atomic_load(&bar[s], __ATOMIC_RELAXED,
                                         __HIP_MEMORY_SCOPE_AGENT) < (unsigned int)NB) {
                    if (__hip_atomic_load(giveup, __ATOMIC_RELAXED,
                                          __HIP_MEMORY_SCOPE_AGENT)) break;
                    if (++iters > SPIN_LIMIT) {
                        __hip_atomic_store(giveup, 1u, __ATOMIC_RELAXED,
                                           __HIP_MEMORY_SCOPE_AGENT);
                        break;
                    }
                    __builtin_amdgcn_s_sleep(8);
                }
            }
        }
    }
    __syncthreads();
}

// ---- Phase D: slice-lockstep (best-effort) aggregate + folded affine epilogue ----
__global__ __launch_bounds__(256)
void bucket_v7(const unsigned int* __restrict__ stab,
               const unsigned int* __restrict__ payload,
               const uint2* __restrict__ xeb,
               const float* __restrict__ xg,
               const float* __restrict__ P,
               float* __restrict__ out,
               unsigned int* bar, unsigned int* giveup) {
    __shared__ float s0[1024], s1[1024], s2[1024], s3[1024];
    __shared__ unsigned int cc[1024];
    __shared__ float sP[48];
    int t = threadIdx.x;
    for (int i = t; i < 1024; i += 256) {
        s0[i] = 0.f; s1[i] = 0.f; s2[i] = 0.f; s3[i] = 0.f; cc[i] = 0u;
    }
    if (t < 48) sP[t] = P[t];
    __syncthreads();

    unsigned int b = blockIdx.x;

    for (int s = 0; s < NS; ++s) {
        unsigned int rs = stab[b * (NS + 1) + s];
        unsigned int re = stab[b * (NS + 1) + s + 1];
        unsigned int i = rs + (unsigned int)t;
        for (; i + 256 < re; i += 512) {
            unsigned int p0 = payload[i];
            unsigned int p1 = payload[i + 256];
            uint2 q0 = xeb[p0 >> 10];
            uint2 q1 = xeb[p1 >> 10];
            unsigned int g0 = p0 & 1023u, g1 = p1 & 1023u;
            atomicAdd(&s0[g0], __uint_as_float(q0.x << 16));
            atomicAdd(&s1[g0], __uint_as_float(q0.x & 0xffff0000u));
            atomicAdd(&s2[g0], __uint_as_float(q0.y << 16));
            atomicAdd(&s3[g0], __uint_as_float(q0.y & 0xffff0000u));
            atomicAdd(&cc[g0], 1u);
            atomicAdd(&s0[g1], __uint_as_float(q1.x << 16));
            atomicAdd(&s1[g1], __uint_as_float(q1.x & 0xffff0000u));
            atomicAdd(&s2[g1], __uint_as_float(q1.y << 16));
            atomicAdd(&s3[g1], __uint_as_float(q1.y & 0xffff0000u));
            atomicAdd(&cc[g1], 1u);
        }
        if (i < re) {
            unsigned int p0 = payload[i];
            uint2 q0 = xeb[p0 >> 10];
            unsigned int g0 = p0 & 1023u;
            atomicAdd(&s0[g0], __uint_as_float(q0.x << 16));
            atomicAdd(&s1[g0], __uint_as_float(q0.x & 0xffff0000u));
            atomicAdd(&s2[g0], __uint_as_float(q0.y << 16));
            atomicAdd(&s3[g0], __uint_as_float(q0.y & 0xffff0000u));
            atomicAdd(&cc[g0], 1u);
        }
        if (s != NS - 1) soft_barrier(bar, giveup, s);
    }
    __syncthreads();

    for (int g = t; g < 1024; g += 256) {
        if (g >= GPB) continue;
        unsigned int G = b * GPB + (unsigned int)g;
        if (G >= N_GUN) continue;
        float cnt = (float)cc[g];
        float inv = 1.0f / fmaxf(cnt, 1.0f);
        float m0 = s0[g] * inv, m1 = s1[g] * inv, m2 = s2[g] * inv, m3 = s3[g] * inv;
        float xv = xg[G];
        float res[OUTD];
#pragma unroll
        for (int o = 0; o < OUTD; ++o) {
            res[o] = m0 * sP[o] + m1 * sP[8 + o] + m2 * sP[16 + o] + m3 * sP[24 + o]
                   + xv * sP[32 + o] + sP[40 + o];
        }
        float4* op = (float4*)(out + (size_t)G * OUTD);
        op[0] = make_float4(res[0], res[1], res[2], res[3]);
        op[1] = make_float4(res[4], res[5], res[6], res[7]);
    }
}

// ================= fallback (atomic path, ~20 MB ws) ========================
__global__ void edge_kernel(const int4* __restrict__ esrc4, const int4* __restrict__ edst4,
                            const float4* __restrict__ xe, float* __restrict__ summed,
                            float* __restrict__ counts) {
    int t = blockIdx.x * blockDim.x + threadIdx.x;
    if (t >= N_EDGES / 4) return;
    int4 s4 = esrc4[t];
    int4 d4 = edst4[t];
    int ss[4] = { s4.x, s4.y, s4.z, s4.w };
    int dd[4] = { d4.x, d4.y, d4.z, d4.w };
#pragma unroll
    for (int k = 0; k < 4; ++k) {
        float4 m = xe[ss[k]];
        float* basep = summed + (size_t)dd[k] * 4;
        atomicAdd(basep + 0, m.x);
        atomicAdd(basep + 1, m.y);
        atomicAdd(basep + 2, m.z);
        atomicAdd(basep + 3, m.w);
        atomicAdd(counts + dd[k], 1.0f);
    }
}

__global__ void gun_kernel(const float4* __restrict__ summed, const float* __restrict__ counts,
                           const float* __restrict__ xg, const float* __restrict__ P,
                           float* __restrict__ out) {
    __shared__ float sP[48];
    if (threadIdx.x < 48) sP[threadIdx.x] = P[threadIdx.x];
    __syncthreads();
    int g = blockIdx.x * blockDim.x + threadIdx.x;
    if (g >= N_GUN) return;
    float4 s = summed[g];
    float cnt = counts[g];
    float inv = 1.0f / fmaxf(cnt, 1.0f);
    float m0 = s.x * inv, m1 = s.y * inv, m2 = s.z * inv, m3 = s.w * inv;
    float xv = xg[g];
    float res[OUTD];
#pragma unroll
    for (int o = 0; o < OUTD; ++o) {
        res[o] = m0 * sP[o] + m1 * sP[8 + o] + m2 * sP[16 + o] + m3 * sP[24 + o]
               + xv * sP[32 + o] + sP[40 + o];
    }
    float4* op = (float4*)(out + (size_t)g * OUTD);
    op[0] = make_float4(res[0], res[1], res[2], res[3]);
    op[1] = make_float4(res[4], res[5], res[6], res[7]);
}

extern "C" void kernel_launch(void* const* d_in, const int* in_sizes, int n_in,
                              void* d_out, int out_size, void* d_ws, size_t ws_size,
                              hipStream_t stream) {
    const float* x_enemy = (const float*)d_in[0];
    const float* x_gun   = (const float*)d_in[1];
    const int*   esrc    = (const int*)d_in[2];
    const int*   edst    = (const int*)d_in[3];
    const float* W_l     = (const float*)d_in[4];
    const float* b_l     = (const float*)d_in[5];
    const float* W_r     = (const float*)d_in[6];
    const float* W_fc    = (const float*)d_in[7];
    const float* b_fc    = (const float*)d_in[8];
    float* out = (float*)d_out;

    // ws layout (u32 units)
    const size_t PAYLOAD_OFF = 0;                            // 16M u32 = 64 MB
    const size_t XEB_OFF     = (size_t)N_EDGES;              // 4M uint2 = 32 MB
    const size_t HIST_OFF    = XEB_OFF + (size_t)N_ENEMY*2;  // +1024 (zeroed)
    const size_t BAR_OFF     = HIST_OFF + NB;                // +16   (zeroed)
    const size_t GU_OFF      = BAR_OFF + NS;                 // +1    (zeroed)
    const size_t OFFS_OFF    = GU_OFF + 1;                   // +1025
    const size_t CURS_OFF    = OFFS_OFF + NB + 1;            // +1024
    const size_t P_OFF       = CURS_OFF + NB;                // +48
    const size_t STAB_OFF    = P_OFF + 48;                   // +NB*(NS+1)
    const size_t NEEDED_FULL = (STAB_OFF + (size_t)NB * (NS + 1)) * sizeof(unsigned int);

    if (ws_size >= NEEDED_FULL) {
        unsigned int* ws      = (unsigned int*)d_ws;
        unsigned int* payload = ws + PAYLOAD_OFF;
        uint2*        xeb     = (uint2*)(ws + XEB_OFF);
        unsigned int* hist    = ws + HIST_OFF;
        unsigned int* bar     = ws + BAR_OFF;
        unsigned int* giveup  = ws + GU_OFF;
        unsigned int* offsets = ws + OFFS_OFF;
        unsigned int* cursor  = ws + CURS_OFF;
        float*        P       = (float*)(ws + P_OFF);
        unsigned int* stab    = ws + STAB_OFF;

        hipMemsetAsync(hist, 0, (NB + NS + 1) * sizeof(unsigned int), stream);
        prep_params<<<1, 64, 0, stream>>>(W_l, b_l, W_r, W_fc, b_fc, P);
        conv_kernel<<<(N_ENEMY + 255) / 256, 256, 0, stream>>>((const uint4*)x_enemy, xeb);
        hist_kernel<<<256, 256, 0, stream>>>((const int4*)edst, hist);
        scan_kernel<<<1, 1024, 0, stream>>>(hist, offsets, cursor);
        scatter_sorted<<<NTILE, 256, 0, stream>>>(esrc, edst, cursor, payload);
        slice_sort<<<NB, 256, 0, stream>>>(offsets, payload, stab);
        bucket_v7<<<NB, 256, 0, stream>>>(stab, payload, xeb, x_gun, P, out, bar, giveup);
    } else {
        float* summed = (float*)d_ws;
        float* counts = summed + (size_t)N_GUN * 4;
        float* P      = counts + N_GUN;
        hipMemsetAsync(d_ws, 0, ((size_t)N_GUN * 5 + 48) * sizeof(float), stream);
        prep_params<<<1, 64, 0, stream>>>(W_l, b_l, W_r, W_fc, b_fc, P);
        int edge_threads = N_EDGES / 4;
        edge_kernel<<<(edge_threads + 255) / 256, 256, 0, stream>>>(
            (const int4*)esrc, (const int4*)edst, (const float4*)x_enemy, summed, counts);
        gun_kernel<<<(N_GUN + 255) / 256, 256, 0, stream>>>(
            (const float4*)summed, counts, x_gun, P, out);
    }
}

// Round 8
// 578.168 us; speedup vs baseline: 4.1600x; 2.8242x over previous
//
#include <hip/hip_runtime.h>

#define N_ENEMY 4000000
#define N_GUN   1000000
#define N_EDGES 16000000
#define HID     64
#define OUTD    8

#define NB 1024                  // buckets (977 guns each)
#define GPB 977                  // guns per bucket
#define TILE 8192                // edges per scatter tile
#define EPT 32                   // edges per thread (TILE/256)
#define NTILE 1954               // ceil(16M / 8192)

#define NS 16                    // src slices (256K enemies = 2MB bf16 each)
#define SEG_CAP 16128            // slice_sort LDS capacity (mean 15625, +4 sigma)

// exact floor(dst/977) for dst <= 1M
__device__ __forceinline__ unsigned int bucket_of(unsigned int dst) {
    return (unsigned int)(((unsigned long long)dst * 1125395730ull) >> 40);
}

__device__ __forceinline__ unsigned int get_xcc() {
    unsigned int x;
    asm("s_getreg_b32 %0, hwreg(HW_REG_XCC_ID)" : "=s"(x));
    return x;
}

// ---- Fold W_l@W_fc (4x8), W_r@W_fc (8), b_l@W_fc + b_fc (8) into P[48] ----
__global__ void prep_params(const float* __restrict__ W_l, const float* __restrict__ b_l,
                            const float* __restrict__ W_r, const float* __restrict__ W_fc,
                            const float* __restrict__ b_fc, float* __restrict__ P) {
    int o = threadIdx.x;
    if (o < OUTD) {
        float a0 = 0.f, a1 = 0.f, a2 = 0.f, a3 = 0.f, r = 0.f, c = 0.f;
        for (int h = 0; h < HID; ++h) {
            float w = W_fc[h * OUTD + o];
            a0 += W_l[0 * HID + h] * w;
            a1 += W_l[1 * HID + h] * w;
            a2 += W_l[2 * HID + h] * w;
            a3 += W_l[3 * HID + h] * w;
            r  += W_r[h] * w;
            c  += b_l[h] * w;
        }
        P[0 * OUTD + o] = a0;
        P[1 * OUTD + o] = a1;
        P[2 * OUTD + o] = a2;
        P[3 * OUTD + o] = a3;
        P[4 * OUTD + o] = r;
        P[5 * OUTD + o] = c + b_fc[o];
    }
}

// ---- Convert x_enemy f32x4 -> bf16x4 (packed into uint2) ----
__device__ __forceinline__ unsigned int rne_bf16(unsigned int u) {
    return (u + 0x7FFFu + ((u >> 16) & 1u)) >> 16;
}
__global__ void conv_kernel(const uint4* __restrict__ xe, uint2* __restrict__ xeb) {
    int i = blockIdx.x * blockDim.x + threadIdx.x;
    if (i >= N_ENEMY) return;
    uint4 v = xe[i];
    uint2 q;
    q.x = rne_bf16(v.x) | (rne_bf16(v.y) << 16);
    q.y = rne_bf16(v.z) | (rne_bf16(v.w) << 16);
    xeb[i] = q;
}

// ---- Phase A: per-tile histogram -> tileh[t][b] (u16, coalesced row) ----
__global__ void hist2_kernel(const int* __restrict__ edst, unsigned short* __restrict__ tileh) {
    __shared__ unsigned int lh[NB];
    int t = threadIdx.x;
    for (int i = t; i < NB; i += 256) lh[i] = 0;
    __syncthreads();
    int ebase = blockIdx.x * TILE;
    int nE = N_EDGES - ebase;
    if (nE > TILE) nE = TILE;
    for (int i = t; i < nE; i += 256)
        atomicAdd(&lh[bucket_of((unsigned)edst[ebase + i])], 1u);
    __syncthreads();
    unsigned short* row = tileh + (size_t)blockIdx.x * NB;
    for (int i = t; i < NB; i += 256) row[i] = (unsigned short)lh[i];
}

// ---- Phase A2: per-bucket exclusive prefix over tiles (in-place on tileh) ----
// 64 blocks; block g handles buckets [16g, 16g+16). Writes tot[b].
__global__ __launch_bounds__(256)
void tile_scan(unsigned short* __restrict__ tileh, unsigned int* __restrict__ tot) {
    __shared__ unsigned int part[256][17];
    int t = threadIdx.x;
    int b0 = blockIdx.x * 16;
    unsigned int loc[16];
#pragma unroll
    for (int j = 0; j < 16; ++j) loc[j] = 0;
    for (int k = 0; k < 8; ++k) {
        int tile = t * 8 + k;
        if (tile < NTILE) {
            const unsigned short* row = tileh + (size_t)tile * NB + b0;
#pragma unroll
            for (int j = 0; j < 16; ++j) loc[j] += row[j];
        }
    }
#pragma unroll
    for (int j = 0; j < 16; ++j) part[t][j] = loc[j];
    __syncthreads();
    if (t < 16) {
        unsigned int acc = 0;
        for (int i = 0; i < 256; ++i) {
            unsigned int v = part[i][t];
            part[i][t] = acc;
            acc += v;
        }
        tot[b0 + t] = acc;
    }
    __syncthreads();
    unsigned int run[16];
#pragma unroll
    for (int j = 0; j < 16; ++j) run[j] = part[t][j];
    for (int k = 0; k < 8; ++k) {
        int tile = t * 8 + k;
        if (tile < NTILE) {
            unsigned short* row = tileh + (size_t)tile * NB + b0;
#pragma unroll
            for (int j = 0; j < 16; ++j) {
                unsigned int c = row[j];
                row[j] = (unsigned short)run[j];
                run[j] += c;
            }
        }
    }
}

// ---- Phase B: exclusive scan of tot -> offsets[NB+1] ----
__global__ void scan_kernel(const unsigned int* __restrict__ tot,
                            unsigned int* __restrict__ offsets) {
    __shared__ unsigned int tmp[1024];
    int t = threadIdx.x;
    unsigned int v0 = (t < NB) ? tot[t] : 0u;
    tmp[t] = v0;
    __syncthreads();
    for (int d = 1; d < 1024; d <<= 1) {
        unsigned int v = (t >= d) ? tmp[t - d] : 0u;
        __syncthreads();
        tmp[t] += v;
        __syncthreads();
    }
    if (t < NB) offsets[t] = tmp[t] - v0;
    if (t == NB - 1) offsets[NB] = tmp[t];
}

// ---- Phase C: tile-sorted partition by bucket (ZERO global atomics) ----
// payload word: (src << 10) | g   where g = dst - bucket*977  (g < 977)
__global__ __launch_bounds__(256, 2)
void scatter_sorted(const int* __restrict__ esrc, const int* __restrict__ edst,
                    const unsigned int* __restrict__ offsets,
                    const unsigned short* __restrict__ tileh,
                    unsigned int* __restrict__ payload) {
    __shared__ unsigned int cnt[NB];
    __shared__ unsigned int base[NB];
    __shared__ unsigned int gb[NB];
    __shared__ unsigned short bOf[TILE];
    __shared__ unsigned int sorted[TILE];
    __shared__ unsigned int partial[256];

    int t = threadIdx.x;
    int tile = blockIdx.x;
    int ebase = tile * TILE;
    int nE = N_EDGES - ebase;
    if (nE > TILE) nE = TILE;

    for (int i = t; i < NB; i += 256) cnt[i] = 0;
    __syncthreads();

    unsigned int w[EPT];
    unsigned int br[EPT];
#pragma unroll
    for (int k = 0; k < EPT; ++k) {
        int idx = k * 256 + t;
        if (idx < nE) {
            unsigned int s = (unsigned int)esrc[ebase + idx];
            unsigned int d = (unsigned int)edst[ebase + idx];
            unsigned int b = bucket_of(d);
            unsigned int g = d - b * GPB;
            unsigned int r = atomicAdd(&cnt[b], 1u);
            w[k]  = (s << 10) | g;
            br[k] = (b << 13) | r;
        } else {
            br[k] = 0xFFFFFFFFu;
        }
    }
    __syncthreads();

    unsigned int loc[4];
    unsigned int s = 0;
#pragma unroll
    for (int j = 0; j < 4; ++j) {
        int b = t * 4 + j;
        unsigned int c = cnt[b];
        loc[j] = s;
        s += c;
    }
    partial[t] = s;
    __syncthreads();
    for (int d = 1; d < 256; d <<= 1) {
        unsigned int v = (t >= d) ? partial[t - d] : 0u;
        __syncthreads();
        partial[t] += v;
        __syncthreads();
    }
    unsigned int excl = (t > 0) ? partial[t - 1] : 0u;
#pragma unroll
    for (int j = 0; j < 4; ++j) {
        int b = t * 4 + j;
        base[b] = excl + loc[j];
    }
    __syncthreads();

    // global base per bucket: offsets[b] + cross-tile exclusive prefix (no atomics)
    const unsigned short* trow = tileh + (size_t)tile * NB;
#pragma unroll
    for (int j = 0; j < 4; ++j) {
        int b = t * 4 + j;
        gb[b] = offsets[b] + (unsigned int)trow[b];
        unsigned int bs = base[b];
        unsigned int c = cnt[b];
        for (unsigned int p = bs; p < bs + c; ++p) bOf[p] = (unsigned short)b;
    }
    __syncthreads();

#pragma unroll
    for (int k = 0; k < EPT; ++k) {
        if (br[k] != 0xFFFFFFFFu) {
            unsigned int b = br[k] >> 13;
            unsigned int r = br[k] & 8191u;
            sorted[base[b] + r] = w[k];
        }
    }
    __syncthreads();

    for (int p = t; p < nE; p += 256) {
        unsigned int b = bOf[p];
        payload[gb[b] + ((unsigned int)p - base[b])] = sorted[p];
    }
}

// ---- Phase C2: per-bucket counting sort by src-slice (slice = w>>28), <=64KB LDS ----
__global__ __launch_bounds__(256)
void slice_sort(const unsigned int* __restrict__ offsets,
                unsigned int* __restrict__ payload,
                unsigned int* __restrict__ stab) {
    __shared__ unsigned int A[SEG_CAP];
    __shared__ unsigned int cnt[NS];
    __shared__ unsigned int base[NS + 1];
    int b = blockIdx.x;
    int t = threadIdx.x;
    unsigned int segS = offsets[b];
    unsigned int segE = offsets[b + 1];
    unsigned int len = segE - segS;

    if (len > SEG_CAP) {
        if (t <= NS) stab[b * (NS + 1) + t] = (t == 0) ? segS : segE;
        return;
    }
    if (t < NS) cnt[t] = 0;
    __syncthreads();
    for (unsigned int i = t; i < len; i += 256) {
        unsigned int w = payload[segS + i];
        A[i] = w;
        atomicAdd(&cnt[w >> 28], 1u);
    }
    __syncthreads();
    if (t == 0) {
        unsigned int acc = 0;
        for (int k = 0; k < NS; ++k) { base[k] = acc; acc += cnt[k]; }
        base[NS] = acc;
    }
    __syncthreads();
    if (t < NS) cnt[t] = 0;
    __syncthreads();
    for (unsigned int i = t; i < len; i += 256) {
        unsigned int w = A[i];
        unsigned int k = w >> 28;
        unsigned int r = atomicAdd(&cnt[k], 1u);
        payload[segS + base[k] + r] = w;
    }
    if (t <= NS) stab[b * (NS + 1) + t] = segS + base[t];
}

// ---- Phase D: XCD-rotated slice walk (no barrier) + folded affine epilogue ----
__global__ __launch_bounds__(256)
void bucket_v8(const unsigned int* __restrict__ stab,
               const unsigned int* __restrict__ payload,
               const uint2* __restrict__ xeb,
               const float* __restrict__ xg,
               const float* __restrict__ P,
               float* __restrict__ out) {
    __shared__ float s0[1024], s1[1024], s2[1024], s3[1024];
    __shared__ unsigned int cc[1024];
    __shared__ float sP[48];
    int t = threadIdx.x;
    for (int i = t; i < 1024; i += 256) {
        s0[i] = 0.f; s1[i] = 0.f; s2[i] = 0.f; s3[i] = 0.f; cc[i] = 0u;
    }
    if (t < 48) sP[t] = P[t];
    __syncthreads();

    unsigned int b = blockIdx.x;
    // rotation only changes slice ORDER; correctness independent of xcc value
    unsigned int rot = (get_xcc() & 7u) << 1;

    for (int si = 0; si < NS; ++si) {
        int s = (int)(((unsigned int)si + rot) & (NS - 1u));
        unsigned int rs = stab[b * (NS + 1) + s];
        unsigned int re = stab[b * (NS + 1) + s + 1];
        unsigned int i = rs + (unsigned int)t;
        for (; i + 256 < re; i += 512) {
            unsigned int p0 = payload[i];
            unsigned int p1 = payload[i + 256];
            uint2 q0 = xeb[p0 >> 10];
            uint2 q1 = xeb[p1 >> 10];
            unsigned int g0 = p0 & 1023u, g1 = p1 & 1023u;
            atomicAdd(&s0[g0], __uint_as_float(q0.x << 16));
            atomicAdd(&s1[g0], __uint_as_float(q0.x & 0xffff0000u));
            atomicAdd(&s2[g0], __uint_as_float(q0.y << 16));
            atomicAdd(&s3[g0], __uint_as_float(q0.y & 0xffff0000u));
            atomicAdd(&cc[g0], 1u);
            atomicAdd(&s0[g1], __uint_as_float(q1.x << 16));
            atomicAdd(&s1[g1], __uint_as_float(q1.x & 0xffff0000u));
            atomicAdd(&s2[g1], __uint_as_float(q1.y << 16));
            atomicAdd(&s3[g1], __uint_as_float(q1.y & 0xffff0000u));
            atomicAdd(&cc[g1], 1u);
        }
        if (i < re) {
            unsigned int p0 = payload[i];
            uint2 q0 = xeb[p0 >> 10];
            unsigned int g0 = p0 & 1023u;
            atomicAdd(&s0[g0], __uint_as_float(q0.x << 16));
            atomicAdd(&s1[g0], __uint_as_float(q0.x & 0xffff0000u));
            atomicAdd(&s2[g0], __uint_as_float(q0.y << 16));
            atomicAdd(&s3[g0], __uint_as_float(q0.y & 0xffff0000u));
            atomicAdd(&cc[g0], 1u);
        }
    }
    __syncthreads();

    for (int g = t; g < 1024; g += 256) {
        if (g >= GPB) continue;
        unsigned int G = b * GPB + (unsigned int)g;
        if (G >= N_GUN) continue;
        float cnt = (float)cc[g];
        float inv = 1.0f / fmaxf(cnt, 1.0f);
        float m0 = s0[g] * inv, m1 = s1[g] * inv, m2 = s2[g] * inv, m3 = s3[g] * inv;
        float xv = xg[G];
        float res[OUTD];
#pragma unroll
        for (int o = 0; o < OUTD; ++o) {
            res[o] = m0 * sP[o] + m1 * sP[8 + o] + m2 * sP[16 + o] + m3 * sP[24 + o]
                   + xv * sP[32 + o] + sP[40 + o];
        }
        float4* op = (float4*)(out + (size_t)G * OUTD);
        op[0] = make_float4(res[0], res[1], res[2], res[3]);
        op[1] = make_float4(res[4], res[5], res[6], res[7]);
    }
}

// ================= fallback (atomic path, ~20 MB ws) ========================
__global__ void edge_kernel(const int4* __restrict__ esrc4, const int4* __restrict__ edst4,
                            const float4* __restrict__ xe, float* __restrict__ summed,
                            float* __restrict__ counts) {
    int t = blockIdx.x * blockDim.x + threadIdx.x;
    if (t >= N_EDGES / 4) return;
    int4 s4 = esrc4[t];
    int4 d4 = edst4[t];
    int ss[4] = { s4.x, s4.y, s4.z, s4.w };
    int dd[4] = { d4.x, d4.y, d4.z, d4.w };
#pragma unroll
    for (int k = 0; k < 4; ++k) {
        float4 m = xe[ss[k]];
        float* basep = summed + (size_t)dd[k] * 4;
        atomicAdd(basep + 0, m.x);
        atomicAdd(basep + 1, m.y);
        atomicAdd(basep + 2, m.z);
        atomicAdd(basep + 3, m.w);
        atomicAdd(counts + dd[k], 1.0f);
    }
}

__global__ void gun_kernel(const float4* __restrict__ summed, const float* __restrict__ counts,
                           const float* __restrict__ xg, const float* __restrict__ P,
                           float* __restrict__ out) {
    __shared__ float sP[48];
    if (threadIdx.x < 48) sP[threadIdx.x] = P[threadIdx.x];
    __syncthreads();
    int g = blockIdx.x * blockDim.x + threadIdx.x;
    if (g >= N_GUN) return;
    float4 s = summed[g];
    float cnt = counts[g];
    float inv = 1.0f / fmaxf(cnt, 1.0f);
    float m0 = s.x * inv, m1 = s.y * inv, m2 = s.z * inv, m3 = s.w * inv;
    float xv = xg[g];
    float res[OUTD];
#pragma unroll
    for (int o = 0; o < OUTD; ++o) {
        res[o] = m0 * sP[o] + m1 * sP[8 + o] + m2 * sP[16 + o] + m3 * sP[24 + o]
               + xv * sP[32 + o] + sP[40 + o];
    }
    float4* op = (float4*)(out + (size_t)g * OUTD);
    op[0] = make_float4(res[0], res[1], res[2], res[3]);
    op[1] = make_float4(res[4], res[5], res[6], res[7]);
}

extern "C" void kernel_launch(void* const* d_in, const int* in_sizes, int n_in,
                              void* d_out, int out_size, void* d_ws, size_t ws_size,
                              hipStream_t stream) {
    const float* x_enemy = (const float*)d_in[0];
    const float* x_gun   = (const float*)d_in[1];
    const int*   esrc    = (const int*)d_in[2];
    const int*   edst    = (const int*)d_in[3];
    const float* W_l     = (const float*)d_in[4];
    const float* b_l     = (const float*)d_in[5];
    const float* W_r     = (const float*)d_in[6];
    const float* W_fc    = (const float*)d_in[7];
    const float* b_fc    = (const float*)d_in[8];
    float* out = (float*)d_out;

    // ws layout (u32 units). tileh (u16, 4MB) aliases the xeb region: tileh is
    // consumed by scatter_sorted, and conv_kernel (which writes xeb) runs after.
    const size_t PAYLOAD_OFF = 0;                            // 16M u32 = 64 MB
    const size_t XEB_OFF     = (size_t)N_EDGES;              // 8M u32 = 32 MB
    const size_t TOT_OFF     = XEB_OFF + (size_t)N_ENEMY*2;  // +1024
    const size_t OFFS_OFF    = TOT_OFF + NB;                 // +1025
    const size_t P_OFF       = OFFS_OFF + NB + 1;            // +48
    const size_t STAB_OFF    = P_OFF + 48;                   // +NB*(NS+1)
    const size_t NEEDED_FULL = (STAB_OFF + (size_t)NB * (NS + 1)) * sizeof(unsigned int);

    if (ws_size >= NEEDED_FULL) {
        unsigned int*   ws      = (unsigned int*)d_ws;
        unsigned int*   payload = ws + PAYLOAD_OFF;
        uint2*          xeb     = (uint2*)(ws + XEB_OFF);
        unsigned short* tileh   = (unsigned short*)(ws + XEB_OFF);  // alias, freed before conv
        unsigned int*   tot     = ws + TOT_OFF;
        unsigned int*   offsets = ws + OFFS_OFF;
        float*          P       = (float*)(ws + P_OFF);
        unsigned int*   stab    = ws + STAB_OFF;

        prep_params<<<1, 64, 0, stream>>>(W_l, b_l, W_r, W_fc, b_fc, P);
        hist2_kernel<<<NTILE, 256, 0, stream>>>(edst, tileh);
        tile_scan<<<NB / 16, 256, 0, stream>>>(tileh, tot);
        scan_kernel<<<1, 1024, 0, stream>>>(tot, offsets);
        scatter_sorted<<<NTILE, 256, 0, stream>>>(esrc, edst, offsets, tileh, payload);
        slice_sort<<<NB, 256, 0, stream>>>(offsets, payload, stab);
        conv_kernel<<<(N_ENEMY + 255) / 256, 256, 0, stream>>>((const uint4*)x_enemy, xeb);
        bucket_v8<<<NB, 256, 0, stream>>>(stab, payload, xeb, x_gun, P, out);
    } else {
        float* summed = (float*)d_ws;
        float* counts = summed + (size_t)N_GUN * 4;
        float* P      = counts + N_GUN;
        hipMemsetAsync(d_ws, 0, ((size_t)N_GUN * 5 + 48) * sizeof(float), stream);
        prep_params<<<1, 64, 0, stream>>>(W_l, b_l, W_r, W_fc, b_fc, P);
        int edge_threads = N_EDGES / 4;
        edge_kernel<<<(edge_threads + 255) / 256, 256, 0, stream>>>(
            (const int4*)esrc, (const int4*)edst, (const float4*)x_enemy, summed, counts);
        gun_kernel<<<(N_GUN + 255) / 256, 256, 0, stream>>>(
            (const float4*)summed, counts, x_gun, P, out);
    }
}

// Round 9
// 577.158 us; speedup vs baseline: 4.1673x; 1.0017x over previous
//
#include <hip/hip_runtime.h>

#define N_ENEMY 4000000
#define N_GUN   1000000
#define N_EDGES 16000000
#define HID     64
#define OUTD    8

#define NB   1024      // dst buckets
#define GPB  977       // guns per dst bucket
#define SB   2048      // src buckets (2048 enemies = 16KB bf16 window)
#define SSHIFT 11
#define RT   4096      // record tile for new path
#define NRT  3907      // ceil(16M/4096)
#define REPT 16        // RT/256
#define TPB  3         // dscatter tiles per src bucket (len <= 12288 @ +50 sigma)
#define DGRID (SB*TPB) // 6144

// round-8 fallback constants
#define T8   8192
#define NT8  1954
#define EPT8 32
#define NS   16
#define SEG_CAP 16128

// exact floor(dst/977) for dst <= 1M
__device__ __forceinline__ unsigned int bucket_of(unsigned int dst) {
    return (unsigned int)(((unsigned long long)dst * 1125395730ull) >> 40);
}

__device__ __forceinline__ unsigned int get_xcc() {
    unsigned int x;
    asm("s_getreg_b32 %0, hwreg(HW_REG_XCC_ID)" : "=s"(x));
    return x;
}

// ---- Fold W_l@W_fc (4x8), W_r@W_fc (8), b_l@W_fc + b_fc (8) into P[48] ----
__global__ void prep_params(const float* __restrict__ W_l, const float* __restrict__ b_l,
                            const float* __restrict__ W_r, const float* __restrict__ W_fc,
                            const float* __restrict__ b_fc, float* __restrict__ P) {
    int o = threadIdx.x;
    if (o < OUTD) {
        float a0 = 0.f, a1 = 0.f, a2 = 0.f, a3 = 0.f, r = 0.f, c = 0.f;
        for (int h = 0; h < HID; ++h) {
            float w = W_fc[h * OUTD + o];
            a0 += W_l[0 * HID + h] * w;
            a1 += W_l[1 * HID + h] * w;
            a2 += W_l[2 * HID + h] * w;
            a3 += W_l[3 * HID + h] * w;
            r  += W_r[h] * w;
            c  += b_l[h] * w;
        }
        P[0 * OUTD + o] = a0;
        P[1 * OUTD + o] = a1;
        P[2 * OUTD + o] = a2;
        P[3 * OUTD + o] = a3;
        P[4 * OUTD + o] = r;
        P[5 * OUTD + o] = c + b_fc[o];
    }
}

// ---- Convert x_enemy f32x4 -> bf16x4 packed in u64 ----
__device__ __forceinline__ unsigned int rne_bf16(unsigned int u) {
    return (u + 0x7FFFu + ((u >> 16) & 1u)) >> 16;
}
__global__ void conv_kernel(const uint4* __restrict__ xe, uint2* __restrict__ xeb) {
    int i = blockIdx.x * blockDim.x + threadIdx.x;
    if (i >= N_ENEMY) return;
    uint4 v = xe[i];
    uint2 q;
    q.x = rne_bf16(v.x) | (rne_bf16(v.y) << 16);
    q.y = rne_bf16(v.z) | (rne_bf16(v.w) << 16);
    xeb[i] = q;
}

// ---- generic tile-prefix kernel: tileh[t][b] -> per-bucket exclusive prefix over
// tiles (in place) + tot[b]. Each block owns 16 buckets; thread t owns tiles
// [t*K, t*K+K). blocks = nbk/16. ----
template<int K>
__global__ __launch_bounds__(256)
void tile_scanT(unsigned short* __restrict__ tileh, unsigned int* __restrict__ tot,
                int nbk, int ntile) {
    __shared__ unsigned int part[256][17];
    int t = threadIdx.x;
    int b0 = blockIdx.x * 16;
    unsigned int loc[16];
#pragma unroll
    for (int j = 0; j < 16; ++j) loc[j] = 0;
    for (int k = 0; k < K; ++k) {
        int tile = t * K + k;
        if (tile < ntile) {
            const unsigned short* row = tileh + (size_t)tile * nbk + b0;
#pragma unroll
            for (int j = 0; j < 16; ++j) loc[j] += row[j];
        }
    }
#pragma unroll
    for (int j = 0; j < 16; ++j) part[t][j] = loc[j];
    __syncthreads();
    if (t < 16) {
        unsigned int acc = 0;
        for (int i = 0; i < 256; ++i) {
            unsigned int v = part[i][t];
            part[i][t] = acc;
            acc += v;
        }
        tot[b0 + t] = acc;
    }
    __syncthreads();
    unsigned int run[16];
#pragma unroll
    for (int j = 0; j < 16; ++j) run[j] = part[t][j];
    for (int k = 0; k < K; ++k) {
        int tile = t * K + k;
        if (tile < ntile) {
            unsigned short* row = tileh + (size_t)tile * nbk + b0;
#pragma unroll
            for (int j = 0; j < 16; ++j) {
                unsigned int c = row[j];
                row[j] = (unsigned short)run[j];
                run[j] += c;
            }
        }
    }
}

// ---- exclusive scans ----
__global__ void scan_kernel(const unsigned int* __restrict__ tot,
                            unsigned int* __restrict__ offsets) {
    __shared__ unsigned int tmp[1024];
    int t = threadIdx.x;
    unsigned int v0 = (t < NB) ? tot[t] : 0u;
    tmp[t] = v0;
    __syncthreads();
    for (int d = 1; d < 1024; d <<= 1) {
        unsigned int v = (t >= d) ? tmp[t - d] : 0u;
        __syncthreads();
        tmp[t] += v;
        __syncthreads();
    }
    if (t < NB) offsets[t] = tmp[t] - v0;
    if (t == NB - 1) offsets[NB] = tmp[t];
}

__global__ void scan2048(const unsigned int* __restrict__ tot,
                         unsigned int* __restrict__ offs) {
    __shared__ unsigned int tmp[1024];
    int t = threadIdx.x;
    unsigned int a = tot[2 * t], b = tot[2 * t + 1];
    unsigned int p = a + b;
    tmp[t] = p;
    __syncthreads();
    for (int d = 1; d < 1024; d <<= 1) {
        unsigned int v = (t >= d) ? tmp[t - d] : 0u;
        __syncthreads();
        tmp[t] += v;
        __syncthreads();
    }
    unsigned int excl = tmp[t] - p;
    offs[2 * t] = excl;
    offs[2 * t + 1] = excl + a;
    if (t == 1023) offs[2048] = tmp[t];
}

// ================= NEW src-major path ========================================

// per-tile src-bucket histogram
__global__ void shist_kernel(const int* __restrict__ esrc, unsigned short* __restrict__ stileh) {
    __shared__ unsigned int lh[SB];
    int t = threadIdx.x;
    for (int i = t; i < SB; i += 256) lh[i] = 0;
    __syncthreads();
    int base = blockIdx.x * RT;
    int n = N_EDGES - base; if (n > RT) n = RT;
    for (int i = t; i < n; i += 256)
        atomicAdd(&lh[((unsigned)esrc[base + i]) >> SSHIFT], 1u);
    __syncthreads();
    unsigned short* row = stileh + (size_t)blockIdx.x * SB;
    for (int i = t; i < SB; i += 256) row[i] = (unsigned short)lh[i];
}

// tile-sort (src,dst) records by src bucket; zero global atomics
__global__ __launch_bounds__(256)
void sscatter8(const int* __restrict__ esrc, const int* __restrict__ edst,
               const unsigned int* __restrict__ sOffs,
               const unsigned short* __restrict__ stileh,
               unsigned int* __restrict__ recS, unsigned int* __restrict__ recD) {
    __shared__ unsigned int cnt[SB];
    __shared__ unsigned int base_[SB];
    __shared__ unsigned short bOf[RT];
    __shared__ unsigned int sortS[RT];
    __shared__ unsigned int sortD[RT];
    __shared__ unsigned int partial[256];
    int t = threadIdx.x;
    int tile = blockIdx.x;
    int ebase = tile * RT;
    int n = N_EDGES - ebase; if (n > RT) n = RT;

    for (int i = t; i < SB; i += 256) cnt[i] = 0;
    __syncthreads();

    unsigned int sv[REPT], dvv[REPT], br[REPT];
#pragma unroll
    for (int k = 0; k < REPT; ++k) {
        int idx = k * 256 + t;
        if (idx < n) {
            unsigned int s = (unsigned int)esrc[ebase + idx];
            unsigned int d = (unsigned int)edst[ebase + idx];
            unsigned int b = s >> SSHIFT;
            unsigned int r = atomicAdd(&cnt[b], 1u);
            sv[k] = s; dvv[k] = d;
            br[k] = (b << 13) | r;
        } else br[k] = 0xFFFFFFFFu;
    }
    __syncthreads();

    unsigned int loc[8];
    unsigned int acc = 0;
#pragma unroll
    for (int j = 0; j < 8; ++j) {
        int b = t * 8 + j;
        unsigned int c = cnt[b];
        loc[j] = acc; acc += c;
    }
    partial[t] = acc;
    __syncthreads();
    for (int d = 1; d < 256; d <<= 1) {
        unsigned int v = (t >= d) ? partial[t - d] : 0u;
        __syncthreads();
        partial[t] += v;
        __syncthreads();
    }
    unsigned int excl = (t > 0) ? partial[t - 1] : 0u;
#pragma unroll
    for (int j = 0; j < 8; ++j) base_[t * 8 + j] = excl + loc[j];
    __syncthreads();

#pragma unroll
    for (int j = 0; j < 8; ++j) {
        int b = t * 8 + j;
        unsigned int bs = base_[b], c = cnt[b];
        for (unsigned int p = bs; p < bs + c; ++p) bOf[p] = (unsigned short)b;
    }
    __syncthreads();

#pragma unroll
    for (int k = 0; k < REPT; ++k) {
        if (br[k] != 0xFFFFFFFFu) {
            unsigned int b = br[k] >> 13, r = br[k] & 8191u;
            sortS[base_[b] + r] = sv[k];
            sortD[base_[b] + r] = dvv[k];
        }
    }
    __syncthreads();

    const unsigned short* trow = stileh + (size_t)tile * SB;
    for (int p = t; p < n; p += 256) {
        unsigned int b = bOf[p];
        unsigned int idx = sOffs[b] + (unsigned int)trow[b] + ((unsigned int)p - base_[b]);
        recS[idx] = sortS[p];
        recD[idx] = sortD[p];
    }
}

// per-(src-bucket, sub-tile) dst histogram over reordered recD
__global__ void dhist_kernel(const unsigned int* __restrict__ recD,
                             const unsigned int* __restrict__ sOffs,
                             unsigned short* __restrict__ dtileh) {
    __shared__ unsigned int lh[NB];
    int t = threadIdx.x;
    for (int i = t; i < NB; i += 256) lh[i] = 0;
    __syncthreads();
    int sb = blockIdx.x / TPB, sub = blockIdx.x % TPB;
    unsigned int segE = sOffs[sb + 1];
    unsigned int st = sOffs[sb] + (unsigned int)sub * RT;
    int n = (st < segE) ? (int)((segE - st < RT) ? (segE - st) : RT) : 0;
    for (int i = t; i < n; i += 256)
        atomicAdd(&lh[bucket_of(recD[st + i])], 1u);
    __syncthreads();
    unsigned short* row = dtileh + (size_t)blockIdx.x * NB;
    for (int i = t; i < NB; i += 256) row[i] = (unsigned short)lh[i];
}

// fused: LDS xeb window gather + tile-sort by dst bucket -> (val,g) streams
__global__ __launch_bounds__(256)
void dscatter(const unsigned int* __restrict__ recS, const unsigned int* __restrict__ recD,
              const unsigned int* __restrict__ sOffs, const unsigned int* __restrict__ dOffs,
              const unsigned short* __restrict__ dtileh,
              const unsigned long long* __restrict__ xeb64,
              unsigned long long* __restrict__ valOut, unsigned short* __restrict__ gOut) {
    __shared__ unsigned long long win[2048];   // 16 KB xeb window
    __shared__ unsigned int cnt[NB];
    __shared__ unsigned int base_[NB];
    __shared__ unsigned short bOf[RT];
    __shared__ unsigned int sortSG[RT];        // (src<<10)|g
    __shared__ unsigned int partial[256];
    int t = threadIdx.x;
    int sb = blockIdx.x / TPB, sub = blockIdx.x % TPB;
    unsigned int segE = sOffs[sb + 1];
    unsigned int st = sOffs[sb] + (unsigned int)sub * RT;
    int n = (st < segE) ? (int)((segE - st < RT) ? (segE - st) : RT) : 0;
    unsigned int eb = (unsigned int)sb << SSHIFT;

    for (int j = t; j < 2048; j += 256) win[j] = xeb64[eb + j];
    for (int i = t; i < NB; i += 256) cnt[i] = 0;
    __syncthreads();

    unsigned int gs[REPT], br[REPT];
#pragma unroll
    for (int k = 0; k < REPT; ++k) {
        int idx = k * 256 + t;
        if (idx < n) {
            unsigned int s = recS[st + idx];
            unsigned int d = recD[st + idx];
            unsigned int b = bucket_of(d);
            unsigned int g = d - b * GPB;
            unsigned int r = atomicAdd(&cnt[b], 1u);
            gs[k] = (s << 10) | g;
            br[k] = (b << 13) | r;
        } else br[k] = 0xFFFFFFFFu;
    }
    __syncthreads();

    unsigned int loc[4];
    unsigned int acc = 0;
#pragma unroll
    for (int j = 0; j < 4; ++j) {
        int b = t * 4 + j;
        unsigned int c = cnt[b];
        loc[j] = acc; acc += c;
    }
    partial[t] = acc;
    __syncthreads();
    for (int d = 1; d < 256; d <<= 1) {
        unsigned int v = (t >= d) ? partial[t - d] : 0u;
        __syncthreads();
        partial[t] += v;
        __syncthreads();
    }
    unsigned int excl = (t > 0) ? partial[t - 1] : 0u;
#pragma unroll
    for (int j = 0; j < 4; ++j) base_[t * 4 + j] = excl + loc[j];
    __syncthreads();

#pragma unroll
    for (int j = 0; j < 4; ++j) {
        int b = t * 4 + j;
        unsigned int bs = base_[b], c = cnt[b];
        for (unsigned int p = bs; p < bs + c; ++p) bOf[p] = (unsigned short)b;
    }
    __syncthreads();

#pragma unroll
    for (int k = 0; k < REPT; ++k) {
        if (br[k] != 0xFFFFFFFFu) {
            unsigned int b = br[k] >> 13, r = br[k] & 8191u;
            sortSG[base_[b] + r] = gs[k];
        }
    }
    __syncthreads();

    const unsigned short* drow = dtileh + (size_t)blockIdx.x * NB;
    for (int p = t; p < n; p += 256) {
        unsigned int b = bOf[p];
        unsigned int w = sortSG[p];
        unsigned int idx = dOffs[b] + (unsigned int)drow[b] + ((unsigned int)p - base_[b]);
        valOut[idx] = win[(w >> 10) - eb];
        gOut[idx] = (unsigned short)(w & 1023u);
    }
}

// aggregate: fully coalesced streams, no gather
__global__ __launch_bounds__(256)
void agg_kernel(const unsigned int* __restrict__ dOffs,
                const unsigned long long* __restrict__ valOut,
                const unsigned short* __restrict__ gOut,
                const float* __restrict__ xg, const float* __restrict__ P,
                float* __restrict__ out) {
    __shared__ float s0[1024], s1[1024], s2[1024], s3[1024];
    __shared__ unsigned int cc[1024];
    __shared__ float sP[48];
    int t = threadIdx.x;
    for (int i = t; i < 1024; i += 256) {
        s0[i] = 0.f; s1[i] = 0.f; s2[i] = 0.f; s3[i] = 0.f; cc[i] = 0u;
    }
    if (t < 48) sP[t] = P[t];
    __syncthreads();

    unsigned int b = blockIdx.x;
    unsigned int st = dOffs[b], en = dOffs[b + 1];
    unsigned int i = st + (unsigned int)t;
    for (; i + 256 < en; i += 512) {
        unsigned long long v0 = valOut[i];
        unsigned long long v1 = valOut[i + 256];
        unsigned int g0 = gOut[i], g1 = gOut[i + 256];
        unsigned int lo0 = (unsigned int)v0, hi0 = (unsigned int)(v0 >> 32);
        unsigned int lo1 = (unsigned int)v1, hi1 = (unsigned int)(v1 >> 32);
        atomicAdd(&s0[g0], __uint_as_float(lo0 << 16));
        atomicAdd(&s1[g0], __uint_as_float(lo0 & 0xffff0000u));
        atomicAdd(&s2[g0], __uint_as_float(hi0 << 16));
        atomicAdd(&s3[g0], __uint_as_float(hi0 & 0xffff0000u));
        atomicAdd(&cc[g0], 1u);
        atomicAdd(&s0[g1], __uint_as_float(lo1 << 16));
        atomicAdd(&s1[g1], __uint_as_float(lo1 & 0xffff0000u));
        atomicAdd(&s2[g1], __uint_as_float(hi1 << 16));
        atomicAdd(&s3[g1], __uint_as_float(hi1 & 0xffff0000u));
        atomicAdd(&cc[g1], 1u);
    }
    if (i < en) {
        unsigned long long v0 = valOut[i];
        unsigned int g0 = gOut[i];
        unsigned int lo0 = (unsigned int)v0, hi0 = (unsigned int)(v0 >> 32);
        atomicAdd(&s0[g0], __uint_as_float(lo0 << 16));
        atomicAdd(&s1[g0], __uint_as_float(lo0 & 0xffff0000u));
        atomicAdd(&s2[g0], __uint_as_float(hi0 << 16));
        atomicAdd(&s3[g0], __uint_as_float(hi0 & 0xffff0000u));
        atomicAdd(&cc[g0], 1u);
    }
    __syncthreads();

    for (int g = t; g < 1024; g += 256) {
        if (g >= GPB) continue;
        unsigned int G = b * GPB + (unsigned int)g;
        if (G >= N_GUN) continue;
        float cnt = (float)cc[g];
        float inv = 1.0f / fmaxf(cnt, 1.0f);
        float m0 = s0[g] * inv, m1 = s1[g] * inv, m2 = s2[g] * inv, m3 = s3[g] * inv;
        float xv = xg[G];
        float res[OUTD];
#pragma unroll
        for (int o = 0; o < OUTD; ++o) {
            res[o] = m0 * sP[o] + m1 * sP[8 + o] + m2 * sP[16 + o] + m3 * sP[24 + o]
                   + xv * sP[32 + o] + sP[40 + o];
        }
        float4* op = (float4*)(out + (size_t)G * OUTD);
        op[0] = make_float4(res[0], res[1], res[2], res[3]);
        op[1] = make_float4(res[4], res[5], res[6], res[7]);
    }
}

// ================= round-8 fallback path (proven, 578us) =====================
__global__ void hist2_kernel(const int* __restrict__ edst, unsigned short* __restrict__ tileh) {
    __shared__ unsigned int lh[NB];
    int t = threadIdx.x;
    for (int i = t; i < NB; i += 256) lh[i] = 0;
    __syncthreads();
    int ebase = blockIdx.x * T8;
    int nE = N_EDGES - ebase;
    if (nE > T8) nE = T8;
    for (int i = t; i < nE; i += 256)
        atomicAdd(&lh[bucket_of((unsigned)edst[ebase + i])], 1u);
    __syncthreads();
    unsigned short* row = tileh + (size_t)blockIdx.x * NB;
    for (int i = t; i < NB; i += 256) row[i] = (unsigned short)lh[i];
}

__global__ __launch_bounds__(256, 2)
void scatter_sorted(const int* __restrict__ esrc, const int* __restrict__ edst,
                    const unsigned int* __restrict__ offsets,
                    const unsigned short* __restrict__ tileh,
                    unsigned int* __restrict__ payload) {
    __shared__ unsigned int cnt[NB];
    __shared__ unsigned int base[NB];
    __shared__ unsigned int gb[NB];
    __shared__ unsigned short bOf[T8];
    __shared__ unsigned int sorted[T8];
    __shared__ unsigned int partial[256];
    int t = threadIdx.x;
    int tile = blockIdx.x;
    int ebase = tile * T8;
    int nE = N_EDGES - ebase;
    if (nE > T8) nE = T8;
    for (int i = t; i < NB; i += 256) cnt[i] = 0;
    __syncthreads();
    unsigned int w[EPT8];
    unsigned int br[EPT8];
#pragma unroll
    for (int k = 0; k < EPT8; ++k) {
        int idx = k * 256 + t;
        if (idx < nE) {
            unsigned int s = (unsigned int)esrc[ebase + idx];
            unsigned int d = (unsigned int)edst[ebase + idx];
            unsigned int b = bucket_of(d);
            unsigned int g = d - b * GPB;
            unsigned int r = atomicAdd(&cnt[b], 1u);
            w[k]  = (s << 10) | g;
            br[k] = (b << 13) | r;
        } else br[k] = 0xFFFFFFFFu;
    }
    __syncthreads();
    unsigned int loc[4];
    unsigned int s = 0;
#pragma unroll
    for (int j = 0; j < 4; ++j) {
        int b = t * 4 + j;
        unsigned int c = cnt[b];
        loc[j] = s; s += c;
    }
    partial[t] = s;
    __syncthreads();
    for (int d = 1; d < 256; d <<= 1) {
        unsigned int v = (t >= d) ? partial[t - d] : 0u;
        __syncthreads();
        partial[t] += v;
        __syncthreads();
    }
    unsigned int excl = (t > 0) ? partial[t - 1] : 0u;
#pragma unroll
    for (int j = 0; j < 4; ++j) base[t * 4 + j] = excl + loc[j];
    __syncthreads();
    const unsigned short* trow = tileh + (size_t)tile * NB;
#pragma unroll
    for (int j = 0; j < 4; ++j) {
        int b = t * 4 + j;
        gb[b] = offsets[b] + (unsigned int)trow[b];
        unsigned int bs = base[b];
        unsigned int c = cnt[b];
        for (unsigned int p = bs; p < bs + c; ++p) bOf[p] = (unsigned short)b;
    }
    __syncthreads();
#pragma unroll
    for (int k = 0; k < EPT8; ++k) {
        if (br[k] != 0xFFFFFFFFu) {
            unsigned int b = br[k] >> 13;
            unsigned int r = br[k] & 8191u;
            sorted[base[b] + r] = w[k];
        }
    }
    __syncthreads();
    for (int p = t; p < nE; p += 256) {
        unsigned int b = bOf[p];
        payload[gb[b] + ((unsigned int)p - base[b])] = sorted[p];
    }
}

__global__ __launch_bounds__(256)
void slice_sort(const unsigned int* __restrict__ offsets,
                unsigned int* __restrict__ payload,
                unsigned int* __restrict__ stab) {
    __shared__ unsigned int A[SEG_CAP];
    __shared__ unsigned int cnt[NS];
    __shared__ unsigned int base[NS + 1];
    int b = blockIdx.x;
    int t = threadIdx.x;
    unsigned int segS = offsets[b];
    unsigned int segE = offsets[b + 1];
    unsigned int len = segE - segS;
    if (len > SEG_CAP) {
        if (t <= NS) stab[b * (NS + 1) + t] = (t == 0) ? segS : segE;
        return;
    }
    if (t < NS) cnt[t] = 0;
    __syncthreads();
    for (unsigned int i = t; i < len; i += 256) {
        unsigned int w = payload[segS + i];
        A[i] = w;
        atomicAdd(&cnt[w >> 28], 1u);
    }
    __syncthreads();
    if (t == 0) {
        unsigned int acc = 0;
        for (int k = 0; k < NS; ++k) { base[k] = acc; acc += cnt[k]; }
        base[NS] = acc;
    }
    __syncthreads();
    if (t < NS) cnt[t] = 0;
    __syncthreads();
    for (unsigned int i = t; i < len; i += 256) {
        unsigned int w = A[i];
        unsigned int k = w >> 28;
        unsigned int r = atomicAdd(&cnt[k], 1u);
        payload[segS + base[k] + r] = w;
    }
    if (t <= NS) stab[b * (NS + 1) + t] = segS + base[t];
}

__global__ __launch_bounds__(256)
void bucket_v8(const unsigned int* __restrict__ stab,
               const unsigned int* __restrict__ payload,
               const uint2* __restrict__ xeb,
               const float* __restrict__ xg,
               const float* __restrict__ P,
               float* __restrict__ out) {
    __shared__ float s0[1024], s1[1024], s2[1024], s3[1024];
    __shared__ unsigned int cc[1024];
    __shared__ float sP[48];
    int t = threadIdx.x;
    for (int i = t; i < 1024; i += 256) {
        s0[i] = 0.f; s1[i] = 0.f; s2[i] = 0.f; s3[i] = 0.f; cc[i] = 0u;
    }
    if (t < 48) sP[t] = P[t];
    __syncthreads();
    unsigned int b = blockIdx.x;
    unsigned int rot = (get_xcc() & 7u) << 1;
    for (int si = 0; si < NS; ++si) {
        int s = (int)(((unsigned int)si + rot) & (NS - 1u));
        unsigned int rs = stab[b * (NS + 1) + s];
        unsigned int re = stab[b * (NS + 1) + s + 1];
        unsigned int i = rs + (unsigned int)t;
        for (; i + 256 < re; i += 512) {
            unsigned int p0 = payload[i];
            unsigned int p1 = payload[i + 256];
            uint2 q0 = xeb[p0 >> 10];
            uint2 q1 = xeb[p1 >> 10];
            unsigned int g0 = p0 & 1023u, g1 = p1 & 1023u;
            atomicAdd(&s0[g0], __uint_as_float(q0.x << 16));
            atomicAdd(&s1[g0], __uint_as_float(q0.x & 0xffff0000u));
            atomicAdd(&s2[g0], __uint_as_float(q0.y << 16));
            atomicAdd(&s3[g0], __uint_as_float(q0.y & 0xffff0000u));
            atomicAdd(&cc[g0], 1u);
            atomicAdd(&s0[g1], __uint_as_float(q1.x << 16));
            atomicAdd(&s1[g1], __uint_as_float(q1.x & 0xffff0000u));
            atomicAdd(&s2[g1], __uint_as_float(q1.y << 16));
            atomicAdd(&s3[g1], __uint_as_float(q1.y & 0xffff0000u));
            atomicAdd(&cc[g1], 1u);
        }
        if (i < re) {
            unsigned int p0 = payload[i];
            uint2 q0 = xeb[p0 >> 10];
            unsigned int g0 = p0 & 1023u;
            atomicAdd(&s0[g0], __uint_as_float(q0.x << 16));
            atomicAdd(&s1[g0], __uint_as_float(q0.x & 0xffff0000u));
            atomicAdd(&s2[g0], __uint_as_float(q0.y << 16));
            atomicAdd(&s3[g0], __uint_as_float(q0.y & 0xffff0000u));
            atomicAdd(&cc[g0], 1u);
        }
    }
    __syncthreads();
    for (int g = t; g < 1024; g += 256) {
        if (g >= GPB) continue;
        unsigned int G = b * GPB + (unsigned int)g;
        if (G >= N_GUN) continue;
        float cnt = (float)cc[g];
        float inv = 1.0f / fmaxf(cnt, 1.0f);
        float m0 = s0[g] * inv, m1 = s1[g] * inv, m2 = s2[g] * inv, m3 = s3[g] * inv;
        float xv = xg[G];
        float res[OUTD];
#pragma unroll
        for (int o = 0; o < OUTD; ++o) {
            res[o] = m0 * sP[o] + m1 * sP[8 + o] + m2 * sP[16 + o] + m3 * sP[24 + o]
                   + xv * sP[32 + o] + sP[40 + o];
        }
        float4* op = (float4*)(out + (size_t)G * OUTD);
        op[0] = make_float4(res[0], res[1], res[2], res[3]);
        op[1] = make_float4(res[4], res[5], res[6], res[7]);
    }
}

// ================= atomic fallback (tiny ws) =================================
__global__ void edge_kernel(const int4* __restrict__ esrc4, const int4* __restrict__ edst4,
                            const float4* __restrict__ xe, float* __restrict__ summed,
                            float* __restrict__ counts) {
    int t = blockIdx.x * blockDim.x + threadIdx.x;
    if (t >= N_EDGES / 4) return;
    int4 s4 = esrc4[t];
    int4 d4 = edst4[t];
    int ss[4] = { s4.x, s4.y, s4.z, s4.w };
    int dd[4] = { d4.x, d4.y, d4.z, d4.w };
#pragma unroll
    for (int k = 0; k < 4; ++k) {
        float4 m = xe[ss[k]];
        float* basep = summed + (size_t)dd[k] * 4;
        atomicAdd(basep + 0, m.x);
        atomicAdd(basep + 1, m.y);
        atomicAdd(basep + 2, m.z);
        atomicAdd(basep + 3, m.w);
        atomicAdd(counts + dd[k], 1.0f);
    }
}

__global__ void gun_kernel(const float4* __restrict__ summed, const float* __restrict__ counts,
                           const float* __restrict__ xg, const float* __restrict__ P,
                           float* __restrict__ out) {
    __shared__ float sP[48];
    if (threadIdx.x < 48) sP[threadIdx.x] = P[threadIdx.x];
    __syncthreads();
    int g = blockIdx.x * blockDim.x + threadIdx.x;
    if (g >= N_GUN) return;
    float4 s = summed[g];
    float cnt = counts[g];
    float inv = 1.0f / fmaxf(cnt, 1.0f);
    float m0 = s.x * inv, m1 = s.y * inv, m2 = s.z * inv, m3 = s.w * inv;
    float xv = xg[g];
    float res[OUTD];
#pragma unroll
    for (int o = 0; o < OUTD; ++o) {
        res[o] = m0 * sP[o] + m1 * sP[8 + o] + m2 * sP[16 + o] + m3 * sP[24 + o]
               + xv * sP[32 + o] + sP[40 + o];
    }
    float4* op = (float4*)(out + (size_t)g * OUTD);
    op[0] = make_float4(res[0], res[1], res[2], res[3]);
    op[1] = make_float4(res[4], res[5], res[6], res[7]);
}

extern "C" void kernel_launch(void* const* d_in, const int* in_sizes, int n_in,
                              void* d_out, int out_size, void* d_ws, size_t ws_size,
                              hipStream_t stream) {
    const float* x_enemy = (const float*)d_in[0];
    const float* x_gun   = (const float*)d_in[1];
    const int*   esrc    = (const int*)d_in[2];
    const int*   edst    = (const int*)d_in[3];
    const float* W_l     = (const float*)d_in[4];
    const float* b_l     = (const float*)d_in[5];
    const float* W_r     = (const float*)d_in[6];
    const float* W_fc    = (const float*)d_in[7];
    const float* b_fc    = (const float*)d_in[8];
    float* out = (float*)d_out;

    // ---- NEW path ws layout (u32 units) ----
    const size_t RECS_OFF   = 0;                                    // 16M
    const size_t RECD_OFF   = RECS_OFF + (size_t)N_EDGES;           // 16M
    const size_t VALO_OFF   = RECD_OFF + (size_t)N_EDGES;           // 32M (u64[16M])
    const size_t GOUT_OFF   = VALO_OFF + (size_t)N_EDGES * 2;       // 8M (u16[16M])
    const size_t XEB_OFF    = GOUT_OFF + (size_t)N_EDGES / 2;       // 8M (u64[4M])
    const size_t STILEH_OFF = XEB_OFF + (size_t)N_ENEMY * 2;        // u16[NRT*SB]
    const size_t DTILEH_OFF = STILEH_OFF + ((size_t)NRT * SB + 1) / 2;
    const size_t STOT_OFF   = DTILEH_OFF + ((size_t)DGRID * NB + 1) / 2;
    const size_t SOFFS_OFF  = STOT_OFF + SB;                        // SB+1
    const size_t DTOT_OFF   = SOFFS_OFF + SB + 1;                   // NB
    const size_t DOFFS_OFF  = DTOT_OFF + NB;                        // NB+1
    const size_t PN_OFF     = DOFFS_OFF + NB + 1;                   // 48
    const size_t NEEDED_NEW = (PN_OFF + 64) * sizeof(unsigned int);

    // ---- round-8 ws layout (u32 units) ----
    const size_t R8_PAYLOAD = 0;
    const size_t R8_XEB     = (size_t)N_EDGES;
    const size_t R8_TOT     = R8_XEB + (size_t)N_ENEMY * 2;
    const size_t R8_OFFS    = R8_TOT + NB;
    const size_t R8_P       = R8_OFFS + NB + 1;
    const size_t R8_STAB    = R8_P + 48;
    const size_t NEEDED_R8  = (R8_STAB + (size_t)NB * (NS + 1)) * sizeof(unsigned int);

    if (ws_size >= NEEDED_NEW) {
        unsigned int*       ws      = (unsigned int*)d_ws;
        unsigned int*       recS    = ws + RECS_OFF;
        unsigned int*       recD    = ws + RECD_OFF;
        unsigned long long* valOut  = (unsigned long long*)(ws + VALO_OFF);
        unsigned short*     gOut    = (unsigned short*)(ws + GOUT_OFF);
        uint2*              xeb     = (uint2*)(ws + XEB_OFF);
        unsigned short*     stileh  = (unsigned short*)(ws + STILEH_OFF);
        unsigned short*     dtileh  = (unsigned short*)(ws + DTILEH_OFF);
        unsigned int*       stot    = ws + STOT_OFF;
        unsigned int*       sOffs   = ws + SOFFS_OFF;
        unsigned int*       dtot    = ws + DTOT_OFF;
        unsigned int*       dOffs   = ws + DOFFS_OFF;
        float*              P       = (float*)(ws + PN_OFF);

        prep_params<<<1, 64, 0, stream>>>(W_l, b_l, W_r, W_fc, b_fc, P);
        conv_kernel<<<(N_ENEMY + 255) / 256, 256, 0, stream>>>((const uint4*)x_enemy, xeb);
        shist_kernel<<<NRT, 256, 0, stream>>>(esrc, stileh);
        tile_scanT<16><<<SB / 16, 256, 0, stream>>>(stileh, stot, SB, NRT);
        scan2048<<<1, 1024, 0, stream>>>(stot, sOffs);
        sscatter8<<<NRT, 256, 0, stream>>>(esrc, edst, sOffs, stileh, recS, recD);
        dhist_kernel<<<DGRID, 256, 0, stream>>>(recD, sOffs, dtileh);
        tile_scanT<24><<<NB / 16, 256, 0, stream>>>(dtileh, dtot, NB, DGRID);
        scan_kernel<<<1, 1024, 0, stream>>>(dtot, dOffs);
        dscatter<<<DGRID, 256, 0, stream>>>(recS, recD, sOffs, dOffs, dtileh,
                                            (const unsigned long long*)xeb, valOut, gOut);
        agg_kernel<<<NB, 256, 0, stream>>>(dOffs, valOut, gOut, x_gun, P, out);
    } else if (ws_size >= NEEDED_R8) {
        unsigned int*   ws      = (unsigned int*)d_ws;
        unsigned int*   payload = ws + R8_PAYLOAD;
        uint2*          xeb     = (uint2*)(ws + R8_XEB);
        unsigned short* tileh   = (unsigned short*)(ws + R8_XEB);   // alias, dead before conv
        unsigned int*   tot     = ws + R8_TOT;
        unsigned int*   offsets = ws + R8_OFFS;
        float*          P       = (float*)(ws + R8_P);
        unsigned int*   stab    = ws + R8_STAB;

        prep_params<<<1, 64, 0, stream>>>(W_l, b_l, W_r, W_fc, b_fc, P);
        hist2_kernel<<<NT8, 256, 0, stream>>>(edst, tileh);
        tile_scanT<8><<<NB / 16, 256, 0, stream>>>(tileh, tot, NB, NT8);
        scan_kernel<<<1, 1024, 0, stream>>>(tot, offsets);
        scatter_sorted<<<NT8, 256, 0, stream>>>(esrc, edst, offsets, tileh, payload);
        slice_sort<<<NB, 256, 0, stream>>>(offsets, payload, stab);
        conv_kernel<<<(N_ENEMY + 255) / 256, 256, 0, stream>>>((const uint4*)x_enemy, xeb);
        bucket_v8<<<NB, 256, 0, stream>>>(stab, payload, xeb, x_gun, P, out);
    } else {
        float* summed = (float*)d_ws;
        float* counts = summed + (size_t)N_GUN * 4;
        float* P      = counts + N_GUN;
        hipMemsetAsync(d_ws, 0, ((size_t)N_GUN * 5 + 48) * sizeof(float), stream);
        prep_params<<<1, 64, 0, stream>>>(W_l, b_l, W_r, W_fc, b_fc, P);
        int edge_threads = N_EDGES / 4;
        edge_kernel<<<(edge_threads + 255) / 256, 256, 0, stream>>>(
            (const int4*)esrc, (const int4*)edst, (const float4*)x_enemy, summed, counts);
        gun_kernel<<<(N_GUN + 255) / 256, 256, 0, stream>>>(
            (const float4*)summed, counts, x_gun, P, out);
    }
}